// Round 9
// baseline (32.019 us; speedup 1.0000x reference)
//
#include <hip/hip_runtime.h>

// Packed volume-render (NeRF ray compositing).
// Pass 1 (starts_kernel): stream ridx (int4), write per-ray segment starts.
// Pass 2 (render_kernel): SIXTEEN LANES PER RAY, 32 samples per iteration
//   (2 consecutive samples per lane, float2 loads):
//   - R*16 = 1M threads = 16384 waves
//   - per 32-sample chunk: 6 float2 load instrs (halved vs 16-wide chunks),
//     one 4-step DPP row scan of pair-sums, one ds_swizzle broadcast
//   - pair math shares exp(-excl): 3 exps per 2 samples (was 4)
//   - base aligned to even (base0 = start & ~1); the one leading sample that
//     may fall before `start` gets tau=0 -> w = exp(-excl)*(1-exp(0)) = 0,
//     so masking tau alone is sufficient
//   - extinction break when carry >= 7 checked per 32 samples (carry at break
//     is only larger than with 16-granularity; dropped tail <= e^-7 ~ 9e-4
//     on alpha, ~2e-3 on rgb << 2e-2 threshold)
//   - Hillis-Steele epilogue: lane 15 holds group totals and writes outputs.

#define THR_TAU 7.0f

template <int CTRL>
__device__ __forceinline__ float dpp_mov0(float v) {
    // value of lane (i - shr) within the 16-lane DPP row; 0 if out of row
    const int r = __builtin_amdgcn_update_dpp(
        0, __float_as_int(v), CTRL, 0xf, 0xf, true);
    return __int_as_float(r);
}

__device__ __forceinline__ float row16_inclusive_scan(float x) {
    x += dpp_mov0<0x111>(x);   // row_shr:1
    x += dpp_mov0<0x112>(x);   // row_shr:2
    x += dpp_mov0<0x114>(x);   // row_shr:4
    x += dpp_mov0<0x118>(x);   // row_shr:8
    return x;                  // lane 15 of each row holds the row total
}

__device__ __forceinline__ float row16_bcast15(float v) {
    // BitMode swizzle: lane' = (lane & 0x10) | 0xF  (within each 32-lane half)
    // -> every lane reads lane 15 of its 16-lane row.
    return __int_as_float(__builtin_amdgcn_ds_swizzle(__float_as_int(v), 0x01F0));
}

__global__ __launch_bounds__(256) void starts_kernel(
    const int* __restrict__ ridx, int* __restrict__ starts,
    int n_samples, int n_rays)
{
    const int t = blockIdx.x * blockDim.x + threadIdx.x;
    const int i0 = t * 4;
    if (i0 >= n_samples) return;

    int prev = (i0 == 0) ? -1 : ridx[i0 - 1];
    const int nj = min(4, n_samples - i0);
    if (nj == 4) {
        const int4 v = *reinterpret_cast<const int4*>(ridx + i0);
        const int cur[4] = {v.x, v.y, v.z, v.w};
        #pragma unroll
        for (int j = 0; j < 4; ++j) {
            const int c = cur[j];
            for (int r = prev + 1; r <= c; ++r) starts[r] = i0 + j;
            prev = c;
        }
    } else {
        for (int j = 0; j < nj; ++j) {
            const int c = ridx[i0 + j];
            for (int r = prev + 1; r <= c; ++r) starts[r] = i0 + j;
            prev = c;
        }
    }
    if (i0 + 4 >= n_samples) {       // last thread closes the table
        for (int r = prev + 1; r <= n_rays; ++r) starts[r] = n_samples;
    }
}

__global__ __launch_bounds__(256) void render_kernel(
    const float* __restrict__ color,    // [N,3]
    const float* __restrict__ density,  // [N,1]
    const float* __restrict__ deltas,   // [N,1]
    const float* __restrict__ depths,   // [N,1]
    const int*   __restrict__ starts,   // [R+1]
    float*       __restrict__ out,      // rgb[3R] | depth[R] | alpha[R] | hit[R]
    int n_rays)
{
    const int tid = blockIdx.x * blockDim.x + threadIdx.x;
    const int r   = tid >> 4;           // ray id (16 lanes per ray)
    const int sub = tid & 15;           // lane within group (== lane in DPP row)
    if (r >= n_rays) return;

    const int start = starts[r];
    const int end   = starts[r + 1];
    const int base0 = start & ~1;       // even alignment for float2 loads

    float carry = 0.0f;                 // cumulative tau from previous chunks
    float aw = 0.0f, ar = 0.0f, ag = 0.0f, ab = 0.0f, ad = 0.0f;

    for (int base = base0; base < end; base += 32) {
        const int i0 = base + 2 * sub;  // this lane's first sample
        float t0 = 0.f, t1 = 0.f;
        float cr0 = 0.f, cg0 = 0.f, cb0 = 0.f, dp0 = 0.f;
        float cr1 = 0.f, cg1 = 0.f, cb1 = 0.f, dp1 = 0.f;

        if (i0 + 1 < end) {             // both samples in-bounds
            const float2 dn = *reinterpret_cast<const float2*>(density + i0);
            const float2 dl = *reinterpret_cast<const float2*>(deltas  + i0);
            const float2 dq = *reinterpret_cast<const float2*>(depths  + i0);
            const float2 ca = *reinterpret_cast<const float2*>(color + 3 * i0);
            const float2 cm = *reinterpret_cast<const float2*>(color + 3 * i0 + 2);
            const float2 cz = *reinterpret_cast<const float2*>(color + 3 * i0 + 4);
            t0 = dn.x * dl.x; t1 = dn.y * dl.y;
            cr0 = ca.x; cg0 = ca.y; cb0 = cm.x; dp0 = dq.x;
            cr1 = cm.y; cg1 = cz.x; cb1 = cz.y; dp1 = dq.y;
            if (i0 < start) t0 = 0.f;   // alignment peel (w0 becomes 0)
        } else if (i0 < end && i0 >= start) {   // single tail sample
            t0  = density[i0] * deltas[i0];
            cr0 = color[3 * i0]; cg0 = color[3 * i0 + 1]; cb0 = color[3 * i0 + 2];
            dp0 = depths[i0];
        }

        // segmented scan of pair-sums within the 16-lane group (DPP, VALU-only)
        const float tp = t0 + t1;
        const float s  = row16_inclusive_scan(tp);
        const float excl0 = carry + (s - tp);       // tau before sample i0
        const float e0 = __expf(-excl0);
        const float x0 = __expf(-t0);
        const float x1 = __expf(-t1);
        const float w0 = e0 * (1.0f - x0);
        const float w1 = e0 * x0 * (1.0f - x1);
        aw += w0 + w1;
        ar += w0 * cr0 + w1 * cr1;
        ag += w0 * cg0 + w1 * cg1;
        ab += w0 * cb0 + w1 * cb1;
        ad += w0 * dp0 + w1 * dp1;
        carry += row16_bcast15(s);                  // chunk total broadcast
        if (carry >= THR_TAU) break;                // extinction: rest <= e^-7
    }

    // group reduction via Hillis-Steele: lane 15 ends with the group totals
    aw = row16_inclusive_scan(aw);
    ar = row16_inclusive_scan(ar);
    ag = row16_inclusive_scan(ag);
    ab = row16_inclusive_scan(ab);
    ad = row16_inclusive_scan(ad);

    if (sub == 15) {
        const float alpha = aw;
        out[3 * r + 0] = (1.0f - alpha) + alpha * ar;   // white background composite
        out[3 * r + 1] = (1.0f - alpha) + alpha * ag;
        out[3 * r + 2] = (1.0f - alpha) + alpha * ab;
        out[3 * n_rays + r] = ad;                       // depth
        out[4 * n_rays + r] = alpha;                    // alpha
        out[5 * n_rays + r] = (alpha > 0.0f) ? 1.0f : 0.0f;  // hit
    }
}

// ---------------- fallback (ws too small): thread-per-ray, binary search ----
__global__ __launch_bounds__(256) void render_fallback(
    const float* __restrict__ color, const float* __restrict__ density,
    const float* __restrict__ deltas, const float* __restrict__ depths,
    const int* __restrict__ ridx, float* __restrict__ out,
    int n_samples, int n_rays)
{
    const int r = blockIdx.x * blockDim.x + threadIdx.x;
    if (r >= n_rays) return;
    int lo = 0, hi = n_samples;
    while (lo < hi) { int m = (lo + hi) >> 1; if (ridx[m] < r) lo = m + 1; else hi = m; }
    int i = lo; int lo2 = lo; hi = n_samples;
    while (lo2 < hi) { int m = (lo2 + hi) >> 1; if (ridx[m] < r + 1) lo2 = m + 1; else hi = m; }
    const int e = lo2;
    float T = 1.f, aw = 0.f, ar = 0.f, ag = 0.f, ab = 0.f, ad = 0.f;
    for (; i < e && T > 1e-5f; ++i) {
        const float t = density[i] * deltas[i];
        const float ee = __expf(-t);
        const float w = T * (1.f - ee);
        aw += w; ar += w * color[3*i]; ag += w * color[3*i+1];
        ab += w * color[3*i+2]; ad += w * depths[i];
        T *= ee;
    }
    const float alpha = aw;
    out[3 * r + 0] = (1.0f - alpha) + alpha * ar;
    out[3 * r + 1] = (1.0f - alpha) + alpha * ag;
    out[3 * r + 2] = (1.0f - alpha) + alpha * ab;
    out[3 * n_rays + r] = ad;
    out[4 * n_rays + r] = alpha;
    out[5 * n_rays + r] = (alpha > 0.0f) ? 1.0f : 0.0f;
}

extern "C" void kernel_launch(void* const* d_in, const int* in_sizes, int n_in,
                              void* d_out, int out_size, void* d_ws, size_t ws_size,
                              hipStream_t stream) {
    const float* color   = (const float*)d_in[0];
    const float* density = (const float*)d_in[1];
    const float* deltas  = (const float*)d_in[2];
    const float* depths  = (const float*)d_in[3];
    const int*   ridx    = (const int*)d_in[4];
    float* out = (float*)d_out;

    const int n_samples = in_sizes[1];      // density element count == N
    const int n_rays    = out_size / 6;     // rgb(3R) + depth(R) + alpha(R) + hit(R)

    const size_t starts_bytes = (size_t)(n_rays + 1) * sizeof(int);

    if (ws_size >= starts_bytes) {
        int* starts = (int*)d_ws;
        const int snthreads = (n_samples + 3) / 4;
        const int sblocks = (snthreads + 255) / 256;
        starts_kernel<<<sblocks, 256, 0, stream>>>(ridx, starts, n_samples, n_rays);

        const long long nthr = (long long)n_rays * 16;
        const int rblocks = (int)((nthr + 255) / 256);
        render_kernel<<<rblocks, 256, 0, stream>>>(
            color, density, deltas, depths, starts, out, n_rays);
    } else {
        const int rblocks = (n_rays + 255) / 256;
        render_fallback<<<rblocks, 256, 0, stream>>>(
            color, density, deltas, depths, ridx, out, n_samples, n_rays);
    }
}